// Round 12
// baseline (179.816 us; speedup 1.0000x reference)
//
#include <hip/hip_runtime.h>

// DCT compression: (32,3,512,512) fp32 -> (32,192,64,64) fp32
// Per 8x8 block: coef[a,u] = sum_{y,x} blk[y,x]*C8[a,y]*C8[u,x]
//   C8[u,y] = cos((u+0.5)*PI*y/8), PI = 3.1415 (module's approximation!)
// norm[a,u] = (a==0||u==0) ? sqrt(2)/8 : 0.25   (NOT separable: [0][0]=sqrt2/8)
// out[b, c*64 + z[a*8+u], hb, wb] = coef[a,u]*norm[a,u] / Qtab[c][z[a*8+u]]
//
// History (measured):
//   R4:  64-thr WGs, grid 6144: 62 us, FETCH 50MB WRITE 98MB, Occ 44%, VGPR 40.
//   R6:  256-thr WGs: 112 us, traffic amplified 2.4x but 3.26 TB/s fabric rate.
//   R7:  2 blk/lane, Occ 23%: 62-67 us (waves x chains invariant).
//   R8/R9: sched_barrier / asm "+v" load pins: VGPR stuck 40, codegen
//        identical -> LLVM sinks loads at IR level; MLP never engaged.
//   R11: XCD-chunked remap + nontemporal stores: 61-62 us, FETCH unchanged
//        -> write-path locality/L3-pollution theory dead. REVERTED.
// Surviving law: BW ~ resident_waves x per-wave in-flight ops. Little's law
// at 2.45 TB/s -> ~1 op in flight per wave. The compiler defeats every
// attempt to batch plain loads (reg-pressure sinking).
// This version: GUARANTEED MLP via __builtin_amdgcn_global_load_lds (no dest
// VGPR -> nothing to sink; side-effecting intrinsic -> can't be reordered
// across the vmcnt fence). Each 1-wave WG stages its 16KB row band in two
// 4-row phases through an 8KB LDS buffer:
//   stage 8x dwordx4 (8 in flight) -> vmcnt(0) -> ds_read+pass1 rows 0-3
//   -> lgkmcnt(0) -> restage rows 4-7 -> vmcnt(0) -> pass1 rows 4-7
// 8KB LDS/WG keeps 16 WGs/CU; VGPR ~90 keeps 4 waves/SIMD.

namespace {

// Compile-time cos: reduce to [-pi,pi] in double, 14-term Taylor (err ~1e-15),
// then round to float. Argument matches the verified device expression:
// ((u+0.5f)*3.1415f)*(y*0.125f).
constexpr double ccos_d(double x) {
    while (x > 3.141592653589793) x -= 6.283185307179586;
    while (x < -3.141592653589793) x += 6.283185307179586;
    const double x2 = x * x;
    double t = 1.0, s = 1.0;
    for (int k = 1; k <= 14; ++k) {
        t *= -x2 / (double)((2 * k - 1) * (2 * k));
        s += t;
    }
    return s;
}

struct Tables {
    float c8[64];      // c8[u*8+y] = cos((u+0.5)*3.1415*y/8); c8[u*8+0] == 1.0f
    float scl[2][64];  // [luma/chroma][a*8+u] = norm(a,u)/Qtab[z(a,u)]
    int   zoff[64];    // z[a*8+u] * 4096 (output element offset)
};

constexpr Tables make_tables() {
    Tables T{};
    for (int u = 0; u < 8; ++u)
        for (int y = 0; y < 8; ++y) {
            const float arg = ((float)u + 0.5f) * 3.1415f * ((float)y * 0.125f);
            T.c8[u * 8 + y] = (float)ccos_d((double)arg);
        }
    // faithful port of reference _zigzag(8); p is the pre-transpose pattern
    int p[64] = {};
    for (int y = 0; y < 8; ++y)
        for (int x = (y & 1); x < 8 - y; x += 2) {
            const int v = x + y + 1;
            p[y * 8 + x] = v * (v + 1) / 2 - x - 1;
        }
    for (int y = 0; y < 8; ++y)
        for (int x = ((y + 1) & 1); x < 8 - y; x += 2) {
            const int v = x + y + 1;
            p[y * 8 + x] = v * (v + 1) / 2 - y - 1;
        }
    for (int y = 7; y >= 0; --y)
        for (int x = 7; x >= 8 - y; --x)
            p[y * 8 + x] = 63 - p[(7 - y) * 8 + (7 - x)];

    // Q=50 -> s=100 -> Q_luma = floor((100*T+50)/100) = T exactly (integers)
    const int QT0[64] = {16,11,10,16,24,40,51,61, 12,12,14,19,26,58,60,55,
                         14,13,16,24,40,57,69,56, 14,17,22,29,51,87,80,62,
                         18,22,37,56,68,109,103,77, 24,35,55,64,81,104,113,92,
                         49,64,78,87,103,121,120,101, 72,92,95,98,112,100,103,99};
    const int QT1[64] = {17,18,24,47,99,99,99,99, 18,21,26,66,99,99,99,99,
                         24,26,56,99,99,99,99,99, 47,66,99,99,99,99,99,99,
                         99,99,99,99,99,99,99,99, 99,99,99,99,99,99,99,99,
                         99,99,99,99,99,99,99,99, 99,99,99,99,99,99,99,99};
    for (int i = 0; i < 64; ++i) {
        const int a = i >> 3, u = i & 7;
        const int zi = p[u * 8 + a];  // z[a*8+u] = p.T[a][u] = p[u*8+a]
        T.zoff[i] = zi << 12;         // * 64*64
        const float nrm = (a == 0 || u == 0) ? 0.17677669529663687f : 0.25f;
        T.scl[0][i] = nrm / (float)QT0[zi];
        T.scl[1][i] = nrm / (float)QT1[zi];
    }
    return T;
}

constexpr Tables TB = make_tables();

}  // namespace

// Grid: 6144 single-wave workgroups (R4 geometry).
//   blockIdx.x = bc*64 + hb;  bc = b*3+c in [0,96);  hb in [0,64)
//   lane (threadIdx.x) = wb.  Each lane: one 8x8 block -> 64 outputs.
__global__ __launch_bounds__(64, 4)
void DCTCompression_25786983645730_kernel(const float* __restrict__ x,
                                          float* __restrict__ out) {
    __shared__ float sm[2048];      // 8 KB: 4 staged image rows of 512 floats

    const int bid = blockIdx.x;
    const int hb  = bid & 63;
    const int bc  = bid >> 6;       // b*3 + c
    const int c   = bc % 3;         // wave-uniform
    const int wb  = threadIdx.x;    // 0..63

    const float* xband = x + (size_t)bc * 262144 + (size_t)hb * 4096;  // 8 rows
    float*       obase = out + (size_t)bc * 262144;
    const int    oo    = hb * 64 + wb;

    float s[8][8];  // pass-1 result: s[y][u]

    // ---- phase A: stage rows 0..3 (8 KB) -- 8 guaranteed-in-flight loads ----
#pragma unroll
    for (int i = 0; i < 8; ++i) {
        // instruction i: image row (i>>1), half (i&1); wave writes 1 KB LDS
        const float* gp = xband + (i >> 1) * 512 + (i & 1) * 256 + wb * 4;
        __builtin_amdgcn_global_load_lds(
            (const __attribute__((address_space(1))) void*)gp,
            (__attribute__((address_space(3))) void*)(sm + i * 256),
            16, 0, 0);
    }
    asm volatile("s_waitcnt vmcnt(0)" ::: "memory");

    // pass 1 rows 0..3: s[y][u] = sum_x blk[y][x] * C8[u][x]
#pragma unroll
    for (int y = 0; y < 4; ++y) {
        const float4 q0 = *reinterpret_cast<const float4*>(&sm[y * 512 + wb * 8]);
        const float4 q1 = *reinterpret_cast<const float4*>(&sm[y * 512 + wb * 8 + 4]);
        const float row[8] = {q0.x, q0.y, q0.z, q0.w, q1.x, q1.y, q1.z, q1.w};
#pragma unroll
        for (int u = 0; u < 8; ++u) {
            float acc = row[0] * TB.c8[u * 8 + 0];  // c8[u][0]==1.0f -> folds
#pragma unroll
            for (int xx = 1; xx < 8; ++xx)
                acc = fmaf(row[xx], TB.c8[u * 8 + xx], acc);
            s[y][u] = acc;
        }
    }

    // all ds_reads must have returned before overwriting the staging buffer
    asm volatile("s_waitcnt lgkmcnt(0)" ::: "memory");

    // ---- phase B: stage rows 4..7 into the same 8 KB ----
#pragma unroll
    for (int i = 0; i < 8; ++i) {
        const float* gp = xband + (4 + (i >> 1)) * 512 + (i & 1) * 256 + wb * 4;
        __builtin_amdgcn_global_load_lds(
            (const __attribute__((address_space(1))) void*)gp,
            (__attribute__((address_space(3))) void*)(sm + i * 256),
            16, 0, 0);
    }
    asm volatile("s_waitcnt vmcnt(0)" ::: "memory");

#pragma unroll
    for (int y = 0; y < 4; ++y) {
        const float4 q0 = *reinterpret_cast<const float4*>(&sm[y * 512 + wb * 8]);
        const float4 q1 = *reinterpret_cast<const float4*>(&sm[y * 512 + wb * 8 + 4]);
        const float row[8] = {q0.x, q0.y, q0.z, q0.w, q1.x, q1.y, q1.z, q1.w};
#pragma unroll
        for (int u = 0; u < 8; ++u) {
            float acc = row[0] * TB.c8[u * 8 + 0];
#pragma unroll
            for (int xx = 1; xx < 8; ++xx)
                acc = fmaf(row[xx], TB.c8[u * 8 + xx], acc);
            s[4 + y][u] = acc;
        }
    }

    // ---- pass 2 (column transform), a-outer; scale + scatter per a ----
#pragma unroll
    for (int a = 0; a < 8; ++a) {
        float acc[8];
#pragma unroll
        for (int u = 0; u < 8; ++u) {
            float v = s[0][u] * TB.c8[a * 8 + 0];   // c8[a][0]==1.0f -> folds
#pragma unroll
            for (int y = 1; y < 8; ++y)
                v = fmaf(s[y][u], TB.c8[a * 8 + y], v);
            acc[u] = v;
        }
#pragma unroll
        for (int u = 0; u < 8; ++u) {
            const int j = a * 8 + u;
            const float sc = (c == 0) ? TB.scl[0][j] : TB.scl[1][j];  // scalar cselect
            obase[oo + TB.zoff[j]] = acc[u] * sc;  // coalesced 256B/wave store
        }
    }
}

extern "C" void kernel_launch(void* const* d_in, const int* in_sizes, int n_in,
                              void* d_out, int out_size, void* d_ws, size_t ws_size,
                              hipStream_t stream) {
    const float* x = (const float*)d_in[0];
    float* out = (float*)d_out;
    // B*C*(H/8) = 32*3*64 = 6144 single-wave workgroups
    DCTCompression_25786983645730_kernel<<<dim3(6144), dim3(64), 0, stream>>>(x, out);
}

// Round 13
// 178.963 us; speedup vs baseline: 1.0048x; 1.0048x over previous
//
#include <hip/hip_runtime.h>

// DCT compression: (32,3,512,512) fp32 -> (32,192,64,64) fp32
// Per 8x8 block: coef[a,u] = sum_{y,x} blk[y,x]*C8[a,y]*C8[u,x]
//   C8[u,y] = cos((u+0.5)*PI*y/8), PI = 3.1415 (module's approximation!)
// norm[a,u] = (a==0||u==0) ? sqrt(2)/8 : 0.25   (NOT separable: [0][0]=sqrt2/8)
// out[b, c*64 + z[a*8+u], hb, wb] = coef[a,u]*norm[a,u] / Qtab[c][z[a*8+u]]
//
// History (measured):
//   R4:  1 blk/lane, grid 6144: 62 us, 2.45 TB/s, Occ 44%, VGPR 40.
//   R6:  256-thr WGs: 112 us (traffic amplified 2.4x). REVERTED.
//   R7:  2 blk/lane: 62-67 us at Occ 23% (occupancy not the lever).
//   R8/R9: load-batch pins: codegen identical -> never engaged.
//   R11: XCD remap + nt-stores: 61-62 us, FETCH unchanged. Theory dead.
//   R12: global_load_lds staging ENGAGED (LDS 8KB, 8 loads in flight):
//        64-65 us -> load-MLP theory DEAD.
// Surviving theory: VMEM INSTRUCTION throughput. All clean variants execute
// exactly 491,520 VMEM instrs and all take 62-66 us (7.9 instr/ns chip-wide,
// ~30% above what the 6.3TB/s float4-copy ubench sustains). Bytes (24 us
// floor) and latency are exonerated. The store side is the fat target:
// 64 instrs/wave x 256 B each.
// This version: R7 2-block structure + per-a-group LDS transpose so each
// plane's two adjacent hb rows (contiguous 512 B in [zi][hb][wb] layout)
// leave as ONE global_store_dwordx2. Per wave: 32 ld + 64 st = 96 VMEM
// (was 160) -> 295K total, 1.67x fewer. Single-wave WG: no barriers needed
// (DS ops in-order per wave). LDS 4 KB/WG.

namespace {

// Compile-time cos: reduce to [-pi,pi] in double, 14-term Taylor (err ~1e-15),
// then round to float. Argument matches the verified device expression:
// ((u+0.5f)*3.1415f)*(y*0.125f).
constexpr double ccos_d(double x) {
    while (x > 3.141592653589793) x -= 6.283185307179586;
    while (x < -3.141592653589793) x += 6.283185307179586;
    const double x2 = x * x;
    double t = 1.0, s = 1.0;
    for (int k = 1; k <= 14; ++k) {
        t *= -x2 / (double)((2 * k - 1) * (2 * k));
        s += t;
    }
    return s;
}

struct Tables {
    float c8[64];      // c8[u*8+y] = cos((u+0.5)*3.1415*y/8); c8[u*8+0] == 1.0f
    float scl[2][64];  // [luma/chroma][a*8+u] = norm(a,u)/Qtab[z(a,u)]
    int   zoff[64];    // z[a*8+u] * 4096 (output element offset)
};

constexpr Tables make_tables() {
    Tables T{};
    for (int u = 0; u < 8; ++u)
        for (int y = 0; y < 8; ++y) {
            const float arg = ((float)u + 0.5f) * 3.1415f * ((float)y * 0.125f);
            T.c8[u * 8 + y] = (float)ccos_d((double)arg);
        }
    // faithful port of reference _zigzag(8); p is the pre-transpose pattern
    int p[64] = {};
    for (int y = 0; y < 8; ++y)
        for (int x = (y & 1); x < 8 - y; x += 2) {
            const int v = x + y + 1;
            p[y * 8 + x] = v * (v + 1) / 2 - x - 1;
        }
    for (int y = 0; y < 8; ++y)
        for (int x = ((y + 1) & 1); x < 8 - y; x += 2) {
            const int v = x + y + 1;
            p[y * 8 + x] = v * (v + 1) / 2 - y - 1;
        }
    for (int y = 7; y >= 0; --y)
        for (int x = 7; x >= 8 - y; --x)
            p[y * 8 + x] = 63 - p[(7 - y) * 8 + (7 - x)];

    // Q=50 -> s=100 -> Q_luma = floor((100*T+50)/100) = T exactly (integers)
    const int QT0[64] = {16,11,10,16,24,40,51,61, 12,12,14,19,26,58,60,55,
                         14,13,16,24,40,57,69,56, 14,17,22,29,51,87,80,62,
                         18,22,37,56,68,109,103,77, 24,35,55,64,81,104,113,92,
                         49,64,78,87,103,121,120,101, 72,92,95,98,112,100,103,99};
    const int QT1[64] = {17,18,24,47,99,99,99,99, 18,21,26,66,99,99,99,99,
                         24,26,56,99,99,99,99,99, 47,66,99,99,99,99,99,99,
                         99,99,99,99,99,99,99,99, 99,99,99,99,99,99,99,99,
                         99,99,99,99,99,99,99,99, 99,99,99,99,99,99,99,99};
    for (int i = 0; i < 64; ++i) {
        const int a = i >> 3, u = i & 7;
        const int zi = p[u * 8 + a];  // z[a*8+u] = p.T[a][u] = p[u*8+a]
        T.zoff[i] = zi << 12;         // * 64*64
        const float nrm = (a == 0 || u == 0) ? 0.17677669529663687f : 0.25f;
        T.scl[0][i] = nrm / (float)QT0[zi];
        T.scl[1][i] = nrm / (float)QT1[zi];
    }
    return T;
}

constexpr Tables TB = make_tables();

}  // namespace

// Grid: 3072 single-wave workgroups.
//   blockIdx.x = bc*32 + pr;  bc = b*3+c in [0,96);  pr in [0,32)
//   lane = wb.  Each lane: blocks (hb0,wb) and (hb0+1,wb), hb0 = pr*2.
__global__ __launch_bounds__(64, 3)
void DCTCompression_25786983645730_kernel(const float* __restrict__ x,
                                          float* __restrict__ out) {
    __shared__ float lds[8 * 128];  // 4 KB: 8 planes x (2 hb rows x 64 wb)

    const int bid = blockIdx.x;
    const int pr  = bid & 31;
    const int bc  = bid >> 5;       // b*3 + c
    const int c   = bc % 3;         // wave-uniform
    const int wb  = threadIdx.x;    // 0..63
    const int hb0 = pr * 2;

    const float* xbase = x + (size_t)bc * 262144;
    float*       obase = out + (size_t)bc * 262144;
    const int    xoA   = hb0 * 4096 + wb * 8;   // block A top row
    const int    xoB   = xoA + 4096;            // block B (next 8 image rows)
    const int    oo2   = hb0 * 64;              // plane-row pair base (elements)

    // ---- load block A, pass 1 -> sA ----
    float4 a0[8], a1[8];
#pragma unroll
    for (int y = 0; y < 8; ++y) {
        a0[y] = *reinterpret_cast<const float4*>(xbase + xoA + y * 512);
        a1[y] = *reinterpret_cast<const float4*>(xbase + xoA + y * 512 + 4);
    }
    float sA[8][8];
#pragma unroll
    for (int y = 0; y < 8; ++y) {
        const float row[8] = {a0[y].x, a0[y].y, a0[y].z, a0[y].w,
                              a1[y].x, a1[y].y, a1[y].z, a1[y].w};
#pragma unroll
        for (int u = 0; u < 8; ++u) {
            float acc = row[0] * TB.c8[u * 8 + 0];  // c8[u][0]==1.0f -> folds
#pragma unroll
            for (int xx = 1; xx < 8; ++xx)
                acc = fmaf(row[xx], TB.c8[u * 8 + xx], acc);
            sA[y][u] = acc;
        }
    }

    // ---- load block B, pass 1 -> sB ----
    float4 b0[8], b1[8];
#pragma unroll
    for (int y = 0; y < 8; ++y) {
        b0[y] = *reinterpret_cast<const float4*>(xbase + xoB + y * 512);
        b1[y] = *reinterpret_cast<const float4*>(xbase + xoB + y * 512 + 4);
    }
    float sB[8][8];
#pragma unroll
    for (int y = 0; y < 8; ++y) {
        const float row[8] = {b0[y].x, b0[y].y, b0[y].z, b0[y].w,
                              b1[y].x, b1[y].y, b1[y].z, b1[y].w};
#pragma unroll
        for (int u = 0; u < 8; ++u) {
            float acc = row[0] * TB.c8[u * 8 + 0];
#pragma unroll
            for (int xx = 1; xx < 8; ++xx)
                acc = fmaf(row[xx], TB.c8[u * 8 + xx], acc);
            sB[y][u] = acc;
        }
    }

    // ---- pass 2 per a-group: compute 8 planes x {A,B}, stage in LDS,
    //      store each plane's 2 adjacent hb rows as ONE dwordx2 (512 B) ----
#pragma unroll
    for (int a = 0; a < 8; ++a) {
#pragma unroll
        for (int u = 0; u < 8; ++u) {
            float vA = sA[0][u] * TB.c8[a * 8 + 0];  // c8[a][0]==1.0f -> folds
            float vB = sB[0][u] * TB.c8[a * 8 + 0];
#pragma unroll
            for (int y = 1; y < 8; ++y) {
                vA = fmaf(sA[y][u], TB.c8[a * 8 + y], vA);
                vB = fmaf(sB[y][u], TB.c8[a * 8 + y], vB);
            }
            const int j = a * 8 + u;
            const float sc = (c == 0) ? TB.scl[0][j] : TB.scl[1][j];
            // stage scaled outputs: [u][0..63] = row hb0 (A), [u][64..127] = hb0+1 (B)
            lds[u * 128 + wb]      = vA * sc;
            lds[u * 128 + 64 + wb] = vB * sc;
        }
        // single wave: DS ops execute in order; compiler inserts lgkmcnt waits.
#pragma unroll
        for (int u = 0; u < 8; ++u) {
            const int j = a * 8 + u;
            // lane l -> elements (2l, 2l+1) of the 128-element pair-row
            const float2 v = *reinterpret_cast<const float2*>(&lds[u * 128 + 2 * wb]);
            *reinterpret_cast<float2*>(obase + TB.zoff[j] + oo2 + 2 * wb) = v;
        }
    }
}

extern "C" void kernel_launch(void* const* d_in, const int* in_sizes, int n_in,
                              void* d_out, int out_size, void* d_ws, size_t ws_size,
                              hipStream_t stream) {
    const float* x = (const float*)d_in[0];
    float* out = (float*)d_out;
    // B*C*(H/8/2) = 32*3*32 = 3072 single-wave workgroups
    DCTCompression_25786983645730_kernel<<<dim3(3072), dim3(64), 0, stream>>>(x, out);
}